// Round 2
// baseline (875.035 us; speedup 1.0000x reference)
//
#include <hip/hip_runtime.h>

// Implicit-GEMM conv3x3(64->256, VALID) + bias + tanh-GELU + spatial mean.
// v4b: identical to v4 (32x32x16 MFMA + explicit SW pipeline), resubmitted
// after an infra-side container failure; unroll pragmas made explicit so the
// pipeline arrays can never be runtime-indexed (scratch hazard).
//
// Structure: 36 flat K-steps (9 taps x 4 ks), B frags double-buffered
// (prefetch +1 step from LDS), A frags triple-buffered (prefetch +2 steps
// from L2-resident 288KB table). Wave tile 64co x 64pix = 2x2 fragments of
// 32x32, acc = 4 x f32x16 = 64 regs. Block tile 256co x 128pix, 8 waves
// (4 co-split x 2 pix-split), 56KB LDS -> 2 blocks/CU.
// Weights pre-swizzled to 32x32x16 A-fragment-linear order
// (row = lane&31, k = (lane>>5)*8+j). C layout: col(pix) = lane&31,
// row(co) = (reg&3) + 8*(reg>>2) + 4*(lane>>5).

typedef __attribute__((ext_vector_type(8))) short short8;
typedef __attribute__((ext_vector_type(4))) float floatx4;
typedef __attribute__((ext_vector_type(16))) float floatx16;
typedef __attribute__((ext_vector_type(4))) unsigned int uintx4;
typedef __attribute__((ext_vector_type(2))) unsigned int uintx2;

#define HO 126
#define CIP 72   // 64 ci + 8 pad shorts: 144B col stride (16B-aligned b128)

__device__ __forceinline__ unsigned int f2bf(float f) {
    unsigned int u = __float_as_uint(f);
    return (u + 0x7FFFu + ((u >> 16) & 1u)) >> 16;   // RNE
}

__device__ __forceinline__ float gelu_t(float y) {
    float p = __builtin_fmaf(0.044715f, y * y, 1.0f);
    float z2 = -2.3022084f * y * p;
    float e = exp2f(z2);
    return y * __builtin_amdgcn_rcpf(1.0f + e);
}

__global__ __launch_bounds__(256)
void prep_kernel(const float* __restrict__ wgt, float* __restrict__ out,
                 unsigned short* __restrict__ wb2) {
    int g = blockIdx.x * 256 + threadIdx.x;
    if (g < 64 * 256) out[g] = 0.f;               // zero the atomic target
    if (g < 147456) {                             // 288 frags * 64 lane * 8
        int j    = g & 7;
        int lane = (g >> 3) & 63;
        int f    = g >> 9;                        // 0..287 = (tap*4+ks)*8+cog
        int cog  = f & 7;
        int ks   = (f >> 3) & 3;
        int tap  = f >> 5;
        int co = cog * 32 + (lane & 31);
        int ci = ks * 16 + (lane >> 5) * 8 + j;   // 32x32x16 A layout
        wb2[g] = (unsigned short)f2bf(wgt[(co * 64 + ci) * 9 + tap]);
    }
}

#define AOFF(t, k, cf) ((size_t)((((t) * 4 + (k)) * 8 + (cf))) * 512)
#define BOFF(t, k, pf) ((((t) / 3) * 130 + ((t) % 3) + (pf) * 32) * CIP + (k) * 16)

__global__ __launch_bounds__(512, 4)
void conv_kernel(const float* __restrict__ x, const float* __restrict__ bias,
                 const unsigned short* __restrict__ wb2, float* __restrict__ out) {
    __shared__ unsigned short xs[3][130][CIP];    // 56160 B -> 2 blocks/CU

    const int bx = blockIdx.x;
    const int n = bx / HO;
    const int h = bx % HO;
    const int tid  = threadIdx.x;
    const int lane = tid & 63;
    const int wave = tid >> 6;
    const int sc = wave & 3;          // co split: coBase = sc*64
    const int sp = wave >> 2;         // pix split: pixBase = sp*64
    const int coBase  = sc * 64;
    const int pixBase = sp * 64;

    // ---- stage x[n][0..63][h..h+2][0..127] -> xs[r][col][ci] bf16 (once) ----
    {
        const int col = tid & 127;
        const int g   = tid >> 7;                 // 0..3, each handles 12 of 48 cells
        const float* xg = x + (size_t)n * 64 * 16384 + h * 128 + col;
#pragma unroll 12
        for (int i = 0; i < 12; ++i) {
            int idx = g * 12 + i;                 // cell = r*16 + cq
            int r  = idx >> 4;
            int cq = idx & 15;                    // ci group of 4
            float v0 = xg[(size_t)(cq * 4 + 0) * 16384 + r * 128];
            float v1 = xg[(size_t)(cq * 4 + 1) * 16384 + r * 128];
            float v2 = xg[(size_t)(cq * 4 + 2) * 16384 + r * 128];
            float v3 = xg[(size_t)(cq * 4 + 3) * 16384 + r * 128];
            uintx2 pk;
            pk.x = f2bf(v0) | (f2bf(v1) << 16);
            pk.y = f2bf(v2) | (f2bf(v3) << 16);
            *reinterpret_cast<uintx2*>(&xs[r][col][cq * 4]) = pk;   // ds_write_b64
        }
    }

    floatx16 acc[2][2];                           // [cf][pf], 64 f32 total
#pragma unroll
    for (int cf = 0; cf < 2; ++cf)
#pragma unroll
        for (int pf = 0; pf < 2; ++pf)
#pragma unroll
            for (int r = 0; r < 16; ++r) acc[cf][pf][r] = 0.f;

    __syncthreads();                              // the ONLY barrier

    union Frag { uintx4 u; short8 s; };
    // Runtime-invariant bases; all loop offsets are compile-time constants.
    const unsigned short* xb = &xs[0][pixBase + (lane & 31)][0] + (lane >> 5) * 8;
    const unsigned short* ab = wb2 + (size_t)(sc * 2) * 512 + lane * 8;

    // ---- software-pipelined main loop: u = tap*4 + ks, 36 steps ----
    Frag a[3][2];                                 // A prefetch depth 2 (24 regs)
    Frag b[2][2];                                 // B prefetch depth 1 (16 regs)
#pragma unroll
    for (int cf = 0; cf < 2; ++cf) {
        a[0][cf].u = *reinterpret_cast<const uintx4*>(ab + AOFF(0, 0, cf));
        a[1][cf].u = *reinterpret_cast<const uintx4*>(ab + AOFF(0, 1, cf));
    }
#pragma unroll
    for (int pf = 0; pf < 2; ++pf)
        b[0][pf].u = *reinterpret_cast<const uintx4*>(xb + BOFF(0, 0, pf));

#pragma unroll 36
    for (int u = 0; u < 36; ++u) {
        // prefetch B for step u+1 (ds latency hidden under this step's MFMAs)
        if (u + 1 < 36) {
            const int t1 = (u + 1) >> 2, k1 = (u + 1) & 3;
#pragma unroll
            for (int pf = 0; pf < 2; ++pf)
                b[(u + 1) & 1][pf].u =
                    *reinterpret_cast<const uintx4*>(xb + BOFF(t1, k1, pf));
        }
        // prefetch A for step u+2 (L2 latency hidden under ~2 steps of MFMAs)
        if (u + 2 < 36) {
            const int t2 = (u + 2) >> 2, k2 = (u + 2) & 3;
#pragma unroll
            for (int cf = 0; cf < 2; ++cf)
                a[(u + 2) % 3][cf].u =
                    *reinterpret_cast<const uintx4*>(ab + AOFF(t2, k2, cf));
        }
#pragma unroll
        for (int cf = 0; cf < 2; ++cf)
#pragma unroll
            for (int pf = 0; pf < 2; ++pf)
                acc[cf][pf] = __builtin_amdgcn_mfma_f32_32x32x16_bf16(
                    a[u % 3][cf].s, b[u & 1][pf].s, acc[cf][pf], 0, 0, 0);
    }

    // ---- epilogue: bias + GELU + masked pixel sum + reduce + atomic mean ----
    // C layout (32x32): col(pix) = lane&31, row(co) = (r&3) + 8*(r>>2) + 4*(lane>>5)
    const float inv = 1.0f / (126.f * 126.f);
    const int colv = pixBase + (lane & 31);
    const bool v0ok = colv < 126;                 // pf = 0
    const bool v1ok = (colv + 32) < 126;          // pf = 1 (masks poison cols too)
    const int uhalf = lane >> 5;
#pragma unroll
    for (int cf = 0; cf < 2; ++cf)
#pragma unroll
        for (int rg = 0; rg < 4; ++rg) {
            const floatx4 bv = *reinterpret_cast<const floatx4*>(
                bias + coBase + cf * 32 + rg * 8 + uhalf * 4);
#pragma unroll
            for (int jj = 0; jj < 4; ++jj) {
                float g0 = gelu_t(acc[cf][0][rg * 4 + jj] + bv[jj]);
                float g1 = gelu_t(acc[cf][1][rg * 4 + jj] + bv[jj]);
                float v = (v0ok ? g0 : 0.f) + (v1ok ? g1 : 0.f);
                v += __shfl_xor(v, 1);
                v += __shfl_xor(v, 2);
                v += __shfl_xor(v, 4);
                v += __shfl_xor(v, 8);
                v += __shfl_xor(v, 16);
                if ((lane & 31) == 0)
                    atomicAdd(&out[n * 256 + coBase + cf * 32 + rg * 8 + uhalf * 4 + jj],
                              v * inv);
            }
        }
}

extern "C" void kernel_launch(void* const* d_in, const int* in_sizes, int n_in,
                              void* d_out, int out_size, void* d_ws, size_t ws_size,
                              hipStream_t stream) {
    const float* x    = (const float*)d_in[0];
    const float* wgt  = (const float*)d_in[1];
    const float* bias = (const float*)d_in[2];
    float* out = (float*)d_out;
    unsigned short* wb2 = (unsigned short*)d_ws;  // 294912 B, 32x32x16-frag-linear bf16

    prep_kernel<<<576, 256, 0, stream>>>(wgt, out, wb2);
    conv_kernel<<<64 * HO, 512, 0, stream>>>(x, bias, wb2, out);
}

// Round 3
// 862.094 us; speedup vs baseline: 1.0150x; 1.0150x over previous
//
#include <hip/hip_runtime.h>

// Implicit-GEMM conv3x3(64->256, VALID) + bias + tanh-GELU + spatial mean.
// v5: revert to the proven v3 inner structure (16x16x32 MFMA, flat tap loop,
// compiler-scheduled), and amortize per-block fixed cost: each block now
// produces TWO output rows from ONE 4-row staged LDS tile (74.9KB -> still
// 2 blocks/CU). Staging per output row drops 3 rows -> 2 rows (1.5x less
// x fetch + f2bf VALU), grid halves to 64x63. Inner loop / epilogue are
// identical to v3 per row (acc reset between rows; atomicAdd per row).
// v4's 32x32 + explicit SW pipeline regressed (464->695us): same pipe
// demand, fewer independent acc chains + rigid lookahead at the 128-reg
// cap beat the compiler's own schedule. Do not re-introduce.

typedef __attribute__((ext_vector_type(8))) short short8;
typedef __attribute__((ext_vector_type(4))) float floatx4;
typedef __attribute__((ext_vector_type(4))) unsigned int uintx4;
typedef __attribute__((ext_vector_type(2))) unsigned int uintx2;

#define HO 126
#define HB 63    // 2 output rows per block
#define CIP 72   // 64 ci + 8 pad shorts: 144B col stride (16B-aligned b128)

__device__ __forceinline__ unsigned int f2bf(float f) {
    unsigned int u = __float_as_uint(f);
    return (u + 0x7FFFu + ((u >> 16) & 1u)) >> 16;   // RNE
}

__device__ __forceinline__ float gelu_t(float y) {
    float p = __builtin_fmaf(0.044715f, y * y, 1.0f);
    float z2 = -2.3022084f * y * p;
    float e = exp2f(z2);
    return y * __builtin_amdgcn_rcpf(1.0f + e);
}

__global__ __launch_bounds__(256)
void prep_kernel(const float* __restrict__ wgt, float* __restrict__ out,
                 unsigned short* __restrict__ wb2) {
    int g = blockIdx.x * 256 + threadIdx.x;
    if (g < 64 * 256) out[g] = 0.f;               // zero the atomic target
    if (g < 147456) {                             // 9 taps * 2 halves * 16 cog * 64 lane * 8
        int j    = g & 7;
        int lane = (g >> 3) & 63;
        int fc   = g >> 9;                        // 0..287
        int cog  = fc & 15;
        int half = (fc >> 4) & 1;
        int tap  = fc >> 5;
        int li = lane & 15, quad = lane >> 4;
        int co = cog * 16 + li;
        int ci = half * 32 + quad * 8 + j;
        wb2[g] = (unsigned short)f2bf(wgt[(co * 64 + ci) * 9 + tap]);
    }
}

__global__ __launch_bounds__(512, 4)
void conv_kernel(const float* __restrict__ x, const float* __restrict__ bias,
                 const unsigned short* __restrict__ wb2, float* __restrict__ out) {
    __shared__ unsigned short xs[4][130][CIP];    // 74880 B -> 2 blocks/CU

    const int bx = blockIdx.x;
    const int n  = bx / HB;
    const int h0 = (bx % HB) * 2;                 // first of two output rows
    const int tid  = threadIdx.x;
    const int lane = tid & 63;
    const int wave = tid >> 6;
    const int li   = lane & 15;
    const int quad = lane >> 4;
    const int sc = wave & 3;          // co split: coBase = sc*64
    const int sp = wave >> 2;         // pix split: pixBase = sp*64
    const int coBase  = sc * 64;
    const int pixBase = sp * 64;

    // ---- stage x[n][0..63][h0..h0+3][0..127] -> xs[r][col][ci] bf16 (once) ----
    {
        const int col = tid & 127;
        const int g   = tid >> 7;                 // 0..3, each handles 16 of 64 cells
        const float* xg = x + (size_t)n * 64 * 16384 + h0 * 128 + col;
#pragma unroll
        for (int i = 0; i < 16; ++i) {
            int idx = g * 16 + i;                 // cell = r*16 + cq
            int r  = idx >> 4;                    // input row 0..3
            int cq = idx & 15;                    // ci group of 4
            float v0 = xg[(size_t)(cq * 4 + 0) * 16384 + r * 128];
            float v1 = xg[(size_t)(cq * 4 + 1) * 16384 + r * 128];
            float v2 = xg[(size_t)(cq * 4 + 2) * 16384 + r * 128];
            float v3 = xg[(size_t)(cq * 4 + 3) * 16384 + r * 128];
            uintx2 pk;
            pk.x = f2bf(v0) | (f2bf(v1) << 16);
            pk.y = f2bf(v2) | (f2bf(v3) << 16);
            *reinterpret_cast<uintx2*>(&xs[r][col][cq * 4]) = pk;   // ds_write_b64
        }
    }

    __syncthreads();                              // the ONLY barrier

    union Frag { uintx4 u; short8 s; };
    // Runtime-invariant bases; all loop offsets are compile-time constants.
    const unsigned short* xbase = &xs[0][pixBase + li][0] + quad * 8;
    const unsigned short* abase = wb2 + (size_t)(sc * 4) * 512 + lane * 8;

    const float inv = 1.0f / (126.f * 126.f);

#pragma unroll
    for (int r0 = 0; r0 < 2; ++r0) {              // two output rows per block
        floatx4 acc[16];                          // [cf 0..3][pf 0..3]
#pragma unroll
        for (int i = 0; i < 16; ++i) acc[i] = (floatx4){0.f, 0.f, 0.f, 0.f};

#pragma unroll
        for (int tap = 0; tap < 9; ++tap) {
            const int kh = tap / 3;
            const int kw = tap % 3;
            Frag a[8];                            // [half][cf]
#pragma unroll
            for (int hf = 0; hf < 2; ++hf)
#pragma unroll
                for (int cf = 0; cf < 4; ++cf)
                    a[hf * 4 + cf].u = *reinterpret_cast<const uintx4*>(
                        abase + (size_t)(((tap * 2 + hf) * 16) + cf) * 512);
#pragma unroll
            for (int hf = 0; hf < 2; ++hf)
#pragma unroll
                for (int pf = 0; pf < 4; ++pf) {
                    Frag b;
                    b.u = *reinterpret_cast<const uintx4*>(
                        xbase + (((r0 + kh) * 130 + kw + pf * 16)) * CIP + hf * 32);
#pragma unroll
                    for (int cf = 0; cf < 4; ++cf)
                        acc[cf * 4 + pf] = __builtin_amdgcn_mfma_f32_16x16x32_bf16(
                            a[hf * 4 + cf].s, b.s, acc[cf * 4 + pf], 0, 0, 0);
                }
        }

        // ---- epilogue: bias + GELU + masked pixel sum + reduce + atomic mean ----
#pragma unroll
        for (int cf = 0; cf < 4; ++cf) {
            const floatx4 bv = *reinterpret_cast<const floatx4*>(
                bias + coBase + cf * 16 + quad * 4);
            floatx4 s = (floatx4){0.f, 0.f, 0.f, 0.f};
#pragma unroll
            for (int pf = 0; pf < 4; ++pf) {
                bool valid = (pixBase + pf * 16 + li) < 126;
#pragma unroll
                for (int r = 0; r < 4; ++r) {
                    float gv = gelu_t(acc[cf * 4 + pf][r] + bv[r]);
                    s[r] += valid ? gv : 0.f;     // select: contains poison-col garbage
                }
            }
#pragma unroll
            for (int r = 0; r < 4; ++r) {
                float v = s[r];
                v += __shfl_xor(v, 1);
                v += __shfl_xor(v, 2);
                v += __shfl_xor(v, 4);
                v += __shfl_xor(v, 8);
                if (li == 0)
                    atomicAdd(&out[n * 256 + coBase + cf * 16 + quad * 4 + r], v * inv);
            }
        }
    }
}

extern "C" void kernel_launch(void* const* d_in, const int* in_sizes, int n_in,
                              void* d_out, int out_size, void* d_ws, size_t ws_size,
                              hipStream_t stream) {
    const float* x    = (const float*)d_in[0];
    const float* wgt  = (const float*)d_in[1];
    const float* bias = (const float*)d_in[2];
    float* out = (float*)d_out;
    unsigned short* wb2 = (unsigned short*)d_ws;  // 294912 B, fragment-linear bf16

    prep_kernel<<<576, 256, 0, stream>>>(wgt, out, wb2);
    conv_kernel<<<64 * HB, 512, 0, stream>>>(x, bias, wb2, out);
}